// Round 9
// baseline (434.203 us; speedup 1.0000x reference)
//
#include <hip/hip_runtime.h>

typedef _Float16 half_t;
typedef _Float16 h8 __attribute__((ext_vector_type(8)));
typedef _Float16 h4 __attribute__((ext_vector_type(4)));
typedef float f4v __attribute__((ext_vector_type(4)));

__device__ __forceinline__ int div196(int m) { return (m * 21400) >> 22; }  // exact for m<=3135

// direct global->LDS DMA, 16B per lane; LDS dest = wave-uniform base + lane*16
__device__ __forceinline__ void gload16(const half_t* g, half_t* l)
{
    __builtin_amdgcn_global_load_lds(
        (const __attribute__((address_space(1))) unsigned int*)g,
        (__attribute__((address_space(3))) unsigned int*)l, 16, 0, 0);
}

// ---------------- prep: cast fp32->fp16 (mode 0) or cast+replicate-4 (mode 1) ----------------
struct PrepArgs {
    const float* src[15];
    half_t* dst[15];
    int n[15];
    int mode[15];
    int lg2[15];
};

__global__ __launch_bounds__(256) void prep_k(PrepArgs a)
{
    const int seg = blockIdx.y;
    const int i8 = (blockIdx.x * 256 + threadIdx.x) * 8;
    if (i8 >= a.n[seg]) return;
    const float* s = a.src[seg] + i8;
    f4v v0 = *(const f4v*)s;
    f4v v1 = *(const f4v*)(s + 4);
    h8 o;
    o[0] = (half_t)v0[0]; o[1] = (half_t)v0[1]; o[2] = (half_t)v0[2]; o[3] = (half_t)v0[3];
    o[4] = (half_t)v1[0]; o[5] = (half_t)v1[1]; o[6] = (half_t)v1[2]; o[7] = (half_t)v1[3];
    if (a.mode[seg] == 0) {
        *(h8*)(a.dst[seg] + i8) = o;
    } else {
        const int lg = a.lg2[seg], ch = 1 << lg;
        const int e = i8 >> lg, d = i8 & (ch - 1);
        half_t* base = a.dst[seg] + ((long long)e << (lg + 2)) + d;
        #pragma unroll
        for (int r = 0; r < 4; ++r) *(h8*)(base + r * ch) = o;
    }
}

// ---------------- staged tile load with row/k-limit masking (register path) ----------------
__device__ __forceinline__ h8 ldtile(const half_t* __restrict__ base, int row, int kb,
                                     int ld, int rowLim, int Klim)
{
    h8 v = {0, 0, 0, 0, 0, 0, 0, 0};
    if (row >= rowLim) return v;
    const half_t* p = base + (long long)row * ld + kb;
    if (kb + 8 <= Klim) return *(const h8*)p;
    #pragma unroll
    for (int e = 0; e < 8; ++e) if (kb + e < Klim) v[e] = p[e];
    return v;
}

// ---------------- batch descriptor, up to 6 heterogeneous jobs ----------------
struct BP {
    const half_t* A[6]; const half_t* B[6]; void* C[6];
    int Mlim[6], Nlim[6], Klim[6], nKt[6], lda[6], ldb[6], ldc[6];
    int divA[6]; long long sAhi[6], sAlo[6];
    int divB[6]; long long sBhi[6], sBlo[6];
    int divC[6]; long long sChi[6], sClo[6];
    long long tStrB[6]; int tComp[6];
    int outMode[6];          // 1 = fp16 normal, 2 = fp16 transposed
    float alpha[6];
    int mT[6], nT[6];
    int cumEnd[5];
    int totW;
};

// ---------------- 64x64 MFMA GEMM (2 waves), fp32 normal out — out-proj ----------------
__global__ __launch_bounds__(128)
void gemm_b(BP P)
{
    __shared__ __align__(16) half_t SM[64 * 72];
    half_t (*As)[32] = (half_t(*)[32])SM;
    half_t (*Bs)[32] = (half_t(*)[32])(SM + 2048);

    int b = blockIdx.x;
    int s = 0, basev = 0;
    #pragma unroll
    for (int i = 0; i < 5; ++i) if (b >= P.cumEnd[i]) { s = i + 1; basev = P.cumEnd[i]; }
    b -= basev;
    const int mTl = P.mT[s], nTl = P.nT[s];
    const int mt = b % mTl;
    const int t2 = b / mTl;
    const int nt = t2 % nTl;
    const int z  = t2 / nTl;

    const half_t* A  = P.A[s] + (long long)(z / P.divA[s]) * P.sAhi[s] + (long long)(z % P.divA[s]) * P.sAlo[s];
    const half_t* Bp = P.B[s] + (long long)(z / P.divB[s]) * P.sBhi[s] + (long long)(z % P.divB[s]) * P.sBlo[s];
    const int Mlim = P.Mlim[s], Klim = P.Klim[s], nKt = P.nKt[s];
    const int lda = P.lda[s], ldb = P.ldb[s], ldc = P.ldc[s];
    const float alpha = P.alpha[s];
    const int m0 = mt * 64, n0 = nt * 64;
    const int tid = threadIdx.x;
    const int lane = tid & 63, w = tid >> 6;
    const int l15 = lane & 15, q = lane >> 4;

    const int r0 = tid >> 2, kg = tid & 3;
    const int r1 = r0 + 32;

    f4v acc[4][2];
    #pragma unroll
    for (int i = 0; i < 4; ++i)
        #pragma unroll
        for (int j = 0; j < 2; ++j) acc[i][j] = (f4v){0.f, 0.f, 0.f, 0.f};

    for (int kt = 0; kt < nKt; ++kt) {
        const int kb = kt * 32 + kg * 8;
        h8 a0 = ldtile(A, m0 + r0, kb, lda, Mlim, Klim);
        h8 a1 = ldtile(A, m0 + r1, kb, lda, Mlim, Klim);
        h8 b0 = ldtile(Bp, n0 + r0, kb, ldb, 1 << 30, Klim);
        h8 b1 = ldtile(Bp, n0 + r1, kb, ldb, 1 << 30, Klim);
        __syncthreads();
        *(h8*)&As[r0][kg * 8] = a0;
        *(h8*)&As[r1][kg * 8] = a1;
        *(h8*)&Bs[r0][kg * 8] = b0;
        *(h8*)&Bs[r1][kg * 8] = b1;
        __syncthreads();
        h8 af[4], bf[2];
        #pragma unroll
        for (int mti = 0; mti < 4; ++mti) af[mti] = *(h8*)&As[mti * 16 + l15][q * 8];
        #pragma unroll
        for (int nti = 0; nti < 2; ++nti) bf[nti] = *(h8*)&Bs[w * 32 + nti * 16 + l15][q * 8];
        #pragma unroll
        for (int mti = 0; mti < 4; ++mti)
            #pragma unroll
            for (int nti = 0; nti < 2; ++nti)
                acc[mti][nti] = __builtin_amdgcn_mfma_f32_16x16x32_f16(af[mti], bf[nti], acc[mti][nti], 0, 0, 0);
    }

    float* Cz = (float*)P.C[s] + (long long)(z / P.divC[s]) * P.sChi[s] + (long long)(z % P.divC[s]) * P.sClo[s];
    #pragma unroll
    for (int mti = 0; mti < 4; ++mti)
        #pragma unroll
        for (int r = 0; r < 4; ++r) {
            const int row = m0 + mti * 16 + q * 4 + r;
            if (row < Mlim) {
                #pragma unroll
                for (int nti = 0; nti < 2; ++nti) {
                    const int col = n0 + w * 32 + nti * 16 + l15;
                    Cz[(long long)row * ldc + col] = acc[mti][nti][r] * alpha;
                }
            }
        }
}

// ---------------- 128x128 MFMA GEMM (256 threads) — K/V/Q projections, ONE launch ----------------
// Staging via global_load_lds width=16 (direct DMA, no VGPR round-trip). LDS is UNPADDED
// [128][32] (deposit = wave base + lane*16). Out-of-range rows are CLAMPED to the last
// valid row (outputs discarded by store guards); K has no tail in any job here.
__global__ __launch_bounds__(256)
void gemm_w(BP P)
{
    __shared__ __align__(16) half_t SMEM[128 * 64];     // As[128][32] + Bs[128][32]; Tt overlay
    half_t (*As)[32] = (half_t(*)[32])SMEM;
    half_t (*Bs)[32] = (half_t(*)[32])(SMEM + 128 * 32);

    const int per = gridDim.x >> 3;
    int wk = (blockIdx.x & 7) * per + (blockIdx.x >> 3);
    if (wk >= P.totW) return;
    int s = 0, basev = 0;
    #pragma unroll
    for (int i = 0; i < 5; ++i) if (wk >= P.cumEnd[i]) { s = i + 1; basev = P.cumEnd[i]; }
    wk -= basev;
    const int mTl = P.mT[s], nTl = P.nT[s];
    const int mt = wk % mTl;
    const int t2 = wk / mTl;
    const int nt = t2 % nTl;
    const int z  = t2 / nTl;

    const half_t* A  = P.A[s] + (long long)(z / P.divA[s]) * P.sAhi[s] + (long long)(z % P.divA[s]) * P.sAlo[s];
    const half_t* Bp = P.B[s] + (long long)(z / P.divB[s]) * P.sBhi[s] + (long long)(z % P.divB[s]) * P.sBlo[s];
    const int Mlim = P.Mlim[s], Nlim = P.Nlim[s], nKt = P.nKt[s];
    const int lda = P.lda[s], ldb = P.ldb[s], ldc = P.ldc[s];
    const float alpha = P.alpha[s];
    const int m0 = mt * 128, n0 = nt * 128;
    const int tid = threadIdx.x;
    const int lane = tid & 63, wv = tid >> 6;
    const int wm = wv & 1, wn = wv >> 1;
    const int l15 = lane & 15, q = lane >> 4;

    // staging coords: wave wv owns rows [wv*32, wv*32+32); lane -> (row=lane>>2, 16B chunk=lane&3)
    const int lrow = wv * 32 + (lane >> 2);
    const int chk8 = (lane & 3) * 8;
    const int rA0 = min(m0 + lrow,      Mlim - 1);
    const int rA1 = min(m0 + lrow + 16, Mlim - 1);
    const int rB0 = min(n0 + lrow,      Nlim - 1);
    const int rB1 = min(n0 + lrow + 16, Nlim - 1);
    const half_t* pA0 = A  + (long long)rA0 * lda + chk8;
    const half_t* pA1 = A  + (long long)rA1 * lda + chk8;
    const half_t* pB0 = Bp + (long long)rB0 * ldb + chk8;
    const half_t* pB1 = Bp + (long long)rB1 * ldb + chk8;
    half_t* lA0 = &As[wv * 32][0];
    half_t* lA1 = &As[wv * 32 + 16][0];
    half_t* lB0 = &Bs[wv * 32][0];
    half_t* lB1 = &Bs[wv * 32 + 16][0];

    f4v acc[4][4];
    #pragma unroll
    for (int i = 0; i < 4; ++i)
        #pragma unroll
        for (int j = 0; j < 4; ++j) acc[i][j] = (f4v){0.f, 0.f, 0.f, 0.f};

    for (int kt = 0; kt < nKt; ++kt) {
        __syncthreads();                       // previous iter's LDS reads complete
        gload16(pA0, lA0);
        gload16(pA1, lA1);
        gload16(pB0, lB0);
        gload16(pB1, lB1);
        pA0 += 32; pA1 += 32; pB0 += 32; pB1 += 32;
        __syncthreads();                       // vmcnt drained before barrier
        h8 af[4], bf[4];
        #pragma unroll
        for (int mi = 0; mi < 4; ++mi) af[mi] = *(h8*)&As[wm * 64 + mi * 16 + l15][q * 8];
        #pragma unroll
        for (int ni = 0; ni < 4; ++ni) bf[ni] = *(h8*)&Bs[wn * 64 + ni * 16 + l15][q * 8];
        #pragma unroll
        for (int mi = 0; mi < 4; ++mi)
            #pragma unroll
            for (int ni = 0; ni < 4; ++ni)
                acc[mi][ni] = __builtin_amdgcn_mfma_f32_16x16x32_f16(af[mi], bf[ni], acc[mi][ni], 0, 0, 0);
    }

    if (P.outMode[s] == 1) {
        half_t* Cz = (half_t*)P.C[s] + (long long)(z / P.divC[s]) * P.sChi[s] + (long long)(z % P.divC[s]) * P.sClo[s];
        #pragma unroll
        for (int mi = 0; mi < 4; ++mi)
            #pragma unroll
            for (int r = 0; r < 4; ++r) {
                const int row = m0 + wm * 64 + mi * 16 + q * 4 + r;
                if (row < Mlim) {
                    #pragma unroll
                    for (int ni = 0; ni < 4; ++ni) {
                        const int col = n0 + wn * 64 + ni * 16 + l15;
                        if (col < Nlim) Cz[(long long)row * ldc + col] = (half_t)(acc[mi][ni][r] * alpha);
                    }
                }
            }
    } else {
        // transpose epilogue, two half-passes through LDS overlay (Tt[128][64] fits 16KB).
        // rows mg >= Mlim must NOT be written (div196 of OOB row walks into next plane).
        half_t (*Tt)[64] = (half_t(*)[64])SMEM;
        half_t* Cz = (half_t*)P.C[s] + (long long)(z / P.divC[s]) * P.sChi[s] + (long long)(z % P.divC[s]) * P.sClo[s];
        const long long tStrB = P.tStrB[s];
        const int jl = tid >> 1, mh = (tid & 1) * 32;
        #pragma unroll
        for (int p = 0; p < 2; ++p) {
            __syncthreads();
            if (wm == p) {
                #pragma unroll
                for (int mi = 0; mi < 4; ++mi)
                    #pragma unroll
                    for (int ni = 0; ni < 4; ++ni) {
                        h4 pk;
                        #pragma unroll
                        for (int r = 0; r < 4; ++r) pk[r] = (half_t)(acc[mi][ni][r] * alpha);
                        *(h4*)&Tt[wn * 64 + ni * 16 + l15][mi * 16 + q * 4] = pk;
                    }
            }
            __syncthreads();
            const int n = n0 + jl;
            if (n < Nlim) {
                #pragma unroll
                for (int g = 0; g < 4; ++g) {
                    const int ml = mh + g * 8;
                    const int mg = m0 + p * 64 + ml;
                    h8 v = *(h8*)&Tt[jl][ml];
                    if (P.tComp[s]) {
                        const int b0 = div196(mg), b1 = div196(mg + 7);
                        if (b0 == b1 && mg + 8 <= Mlim) {
                            half_t* rp = Cz + (long long)b0 * tStrB + (long long)n * ldc + (mg - 196 * b0);
                            h4 lo = {v[0], v[1], v[2], v[3]};
                            h4 hi = {v[4], v[5], v[6], v[7]};
                            *(h4*)rp = lo;
                            *(h4*)(rp + 4) = hi;
                        } else {
                            #pragma unroll
                            for (int e = 0; e < 8; ++e) {
                                const int m = mg + e;
                                if (m < Mlim) {
                                    const int bb = div196(m);
                                    Cz[(long long)bb * tStrB + (long long)n * ldc + (m - 196 * bb)] = v[e];
                                }
                            }
                        }
                    } else {
                        if (mg + 8 <= Mlim) {
                            *(h8*)(Cz + (long long)n * ldc + mg) = v;
                        } else {
                            #pragma unroll
                            for (int e = 0; e < 8; ++e)
                                if (mg + e < Mlim) Cz[(long long)n * ldc + mg + e] = v[e];
                        }
                    }
                }
            }
        }
    }
}

// ---------------- scores: A-strip-resident GEMM + fused IN-stat partials ----------------
struct ScP {
    const half_t* Qt[4];
    const half_t* KT;
    half_t* C[4];
    float* Part[4];
    int Mlim[4];
    long long sA[4], sC[4];
    float alpha;
};

__global__ __launch_bounds__(256)
void gemm_s(ScP P)
{
    __shared__ __align__(16) half_t As[128][232];   // full-K strip (196 -> zero-pad)
    __shared__ __align__(16) half_t Bs[128][72];    // 64-wide B chunk
    __shared__ float red[8];

    const int per = gridDim.x >> 3;                 // 512/8 = 64 -> 8 z per XCD
    int wk = (blockIdx.x & 7) * per + (blockIdx.x >> 3);
    const int z = wk >> 3, r = wk & 7;
    int s, mt;
    if (r < 1)      { s = 0; mt = 0; }
    else if (r < 2) { s = 1; mt = 0; }
    else if (r < 4) { s = 2; mt = r - 2; }
    else            { s = 3; mt = r - 4; }
    const int b = z >> 2, h = z & 3;

    const half_t* A = P.Qt[s] + (long long)z * P.sA[s] + (long long)mt * 128 * 208;
    const half_t* B = P.KT + (long long)h * 3194880 + (long long)b * 199680;
    const int rowLim = P.Mlim[s] - mt * 128;
    const float alpha = P.alpha;

    const int tid = threadIdx.x;
    const int lane = tid & 63, wv = tid >> 6;
    const int wm = wv & 1, wn = wv >> 1;
    const int l15 = lane & 15, q = lane >> 4;
    const int r0 = tid >> 2, kg = tid & 3;

    #pragma unroll
    for (int c = 0; c < 7; ++c) {
        const int kb = c * 32 + kg * 8;
        h8 a0 = ldtile(A, r0, kb, 208, rowLim, 196);
        h8 a1 = ldtile(A, r0 + 64, kb, 208, rowLim, 196);
        *(h8*)&As[r0][kb] = a0;
        *(h8*)&As[r0 + 64][kb] = a1;
    }

    half_t* Cz = P.C[s] + (long long)z * P.sC[s] + (long long)mt * 128 * 960;
    float sv = 0.f, qq = 0.f;

    for (int nt = 0; nt < 8; ++nt) {
        f4v acc[4][4];
        #pragma unroll
        for (int i = 0; i < 4; ++i)
            #pragma unroll
            for (int j = 0; j < 4; ++j) acc[i][j] = (f4v){0.f, 0.f, 0.f, 0.f};

        const int j0 = nt * 128;
        #pragma unroll
        for (int c2 = 0; c2 < 4; ++c2) {
            h8 b00 = ldtile(B, j0 + r0,      c2 * 64 + kg * 8,      208, 960, 196);
            h8 b01 = ldtile(B, j0 + r0,      c2 * 64 + 32 + kg * 8, 208, 960, 196);
            h8 b10 = ldtile(B, j0 + r0 + 64, c2 * 64 + kg * 8,      208, 960, 196);
            h8 b11 = ldtile(B, j0 + r0 + 64, c2 * 64 + 32 + kg * 8, 208, 960, 196);
            __syncthreads();
            *(h8*)&Bs[r0][kg * 8] = b00;
            *(h8*)&Bs[r0][32 + kg * 8] = b01;
            *(h8*)&Bs[r0 + 64][kg * 8] = b10;
            *(h8*)&Bs[r0 + 64][32 + kg * 8] = b11;
            __syncthreads();
            const int nkk = (c2 < 3) ? 2 : 1;
            for (int kk = 0; kk < nkk; ++kk) {
                const int base = c2 * 64 + kk * 32;
                h8 af[4], bf[4];
                #pragma unroll
                for (int mi = 0; mi < 4; ++mi) af[mi] = *(h8*)&As[wm * 64 + mi * 16 + l15][base + q * 8];
                #pragma unroll
                for (int ni = 0; ni < 4; ++ni) bf[ni] = *(h8*)&Bs[wn * 64 + ni * 16 + l15][kk * 32 + q * 8];
                #pragma unroll
                for (int mi = 0; mi < 4; ++mi)
                    #pragma unroll
                    for (int ni = 0; ni < 4; ++ni)
                        acc[mi][ni] = __builtin_amdgcn_mfma_f32_16x16x32_f16(af[mi], bf[ni], acc[mi][ni], 0, 0, 0);
            }
        }
        #pragma unroll
        for (int mi = 0; mi < 4; ++mi)
            #pragma unroll
            for (int rr = 0; rr < 4; ++rr) {
                const int rowl = wm * 64 + mi * 16 + q * 4 + rr;
                #pragma unroll
                for (int ni = 0; ni < 4; ++ni) {
                    const int col = j0 + wn * 64 + ni * 16 + l15;
                    const float v = acc[mi][ni][rr] * alpha;
                    sv += v; qq += v * v;
                    if (rowl < rowLim && col < 960)
                        Cz[(long long)rowl * 960 + col] = (half_t)v;
                }
            }
    }

    #pragma unroll
    for (int o = 32; o > 0; o >>= 1) {
        sv += __shfl_down(sv, o, 64);
        qq += __shfl_down(qq, o, 64);
    }
    if (lane == 0) { red[wv] = sv; red[4 + wv] = qq; }
    __syncthreads();
    if (tid == 0) {
        float* PO = P.Part[s] + (long long)z * 240 + mt * 2;
        PO[0] = red[0] + red[1] + red[2] + red[3];
        PO[1] = red[4] + red[5] + red[6] + red[7];
    }
}

// ---------------- ctx: fused IN-scale + exp + PV GEMM + denominator normalize ----------------
// Software-pipelined: loads for iter k+1 issue before MFMA of iter k.
struct CtxP {
    const half_t* V;
    const half_t* S[4];
    half_t* C[4];
    const float* Part[4];
    int ch[4];
    int nPart[4];
    float pinv[4];
};

__global__ __launch_bounds__(256)
void ctx_k(CtxP P)
{
    __shared__ __align__(16) half_t As[128][40];
    __shared__ __align__(16) half_t Bs[128][40];
    __shared__ float denomP[128][4];
    __shared__ float denom[128];

    const int per = gridDim.x >> 3;                 // 1024/8 = 128 -> 8 z per XCD
    int wk = (blockIdx.x & 7) * per + (blockIdx.x >> 3);
    const int z = wk >> 4;
    const int r = wk & 15;
    int s, mt, nt;
    if (r < 2)      { s = 0; mt = r;            nt = 0; }
    else if (r < 4) { s = 1; mt = r - 2;        nt = 0; }
    else if (r < 8) { s = 2; mt = (r - 4) >> 1; nt = (r - 4) & 1; }
    else            { s = 3; mt = (r - 8) >> 2; nt = (r - 8) & 3; }
    const int b = z >> 2, h = z & 3;
    const int chS = P.ch[s];

    const float* part = P.Part[s] + (long long)z * 240;
    float Ssum = 0.f, Qsum = 0.f;
    for (int i = 0; i < P.nPart[s]; ++i) { Ssum += part[i * 2]; Qsum += part[i * 2 + 1]; }
    const float mn = Ssum * P.pinv[s];
    const float rs = rsqrtf(fmaxf(Qsum * P.pinv[s] - mn * mn, 0.f) + 1e-5f);

    const half_t* Av  = P.V + (long long)h * 3010560 + (long long)b * 188160;   // [196][960]
    const half_t* Bsc = P.S[s] + (long long)z * 960 * chS;                      // [ch][960] raw
    const int m0 = mt * 128, n0 = nt * 128;

    const int tid = threadIdx.x;
    const int lane = tid & 63, wv = tid >> 6;
    const int wm = wv & 1, wn = wv >> 1;
    const int l15 = lane & 15, q = lane >> 4;
    const int r0 = tid >> 2, kg = tid & 3;
    const int d0 = n0 + r0, d1 = n0 + r0 + 64;
    const bool ok0 = d0 < chS, ok1 = d1 < chS;

    f4v acc[4][4];
    #pragma unroll
    for (int i = 0; i < 4; ++i)
        #pragma unroll
        for (int j = 0; j < 4; ++j) acc[i][j] = (f4v){0.f, 0.f, 0.f, 0.f};

    float ds0 = 0.f, ds1 = 0.f;

    h8 a0n = ldtile(Av, m0 + r0, kg * 8, 960, 196, 960);
    h8 a1n = ldtile(Av, m0 + r0 + 64, kg * 8, 960, 196, 960);
    h8 s0n = {0,0,0,0,0,0,0,0}, s1n = {0,0,0,0,0,0,0,0};
    if (ok0) s0n = *(const h8*)(Bsc + (long long)d0 * 960 + kg * 8);
    if (ok1) s1n = *(const h8*)(Bsc + (long long)d1 * 960 + kg * 8);

    for (int kt = 0; kt < 30; ++kt) {
        h8 e0 = {0,0,0,0,0,0,0,0}, e1 = {0,0,0,0,0,0,0,0};
        if (ok0) {
            #pragma unroll
            for (int e = 0; e < 8; ++e) { float ev = __expf((float)s0n[e] * rs); ds0 += ev; e0[e] = (half_t)ev; }
        }
        if (ok1) {
            #pragma unroll
            for (int e = 0; e < 8; ++e) { float ev = __expf((float)s1n[e] * rs); ds1 += ev; e1[e] = (half_t)ev; }
        }
        h8 a0c = a0n, a1c = a1n;
        __syncthreads();
        *(h8*)&As[r0][kg * 8] = a0c;
        *(h8*)&As[r0 + 64][kg * 8] = a1c;
        *(h8*)&Bs[r0][kg * 8] = e0;
        *(h8*)&Bs[r0 + 64][kg * 8] = e1;
        __syncthreads();
        if (kt < 29) {
            const int kb = (kt + 1) * 32 + kg * 8;
            a0n = ldtile(Av, m0 + r0, kb, 960, 196, 960);
            a1n = ldtile(Av, m0 + r0 + 64, kb, 960, 196, 960);
            if (ok0) s0n = *(const h8*)(Bsc + (long long)d0 * 960 + kb);
            if (ok1) s1n = *(const h8*)(Bsc + (long long)d1 * 960 + kb);
        }
        h8 af[4], bf[4];
        #pragma unroll
        for (int mi = 0; mi < 4; ++mi) af[mi] = *(h8*)&As[wm * 64 + mi * 16 + l15][q * 8];
        #pragma unroll
        for (int ni = 0; ni < 4; ++ni) bf[ni] = *(h8*)&Bs[wn * 64 + ni * 16 + l15][q * 8];
        #pragma unroll
        for (int mi = 0; mi < 4; ++mi)
            #pragma unroll
            for (int ni = 0; ni < 4; ++ni)
                acc[mi][ni] = __builtin_amdgcn_mfma_f32_16x16x32_f16(af[mi], bf[ni], acc[mi][ni], 0, 0, 0);
    }

    denomP[r0][kg] = ds0;
    denomP[r0 + 64][kg] = ds1;
    __syncthreads();
    if (tid < 128) denom[tid] = denomP[tid][0] + denomP[tid][1] + denomP[tid][2] + denomP[tid][3];
    __syncthreads();

    half_t* Cz = P.C[s] + (long long)b * 784 * chS + (long long)h * chS;
    const int ldc = 4 * chS;
    #pragma unroll
    for (int ni = 0; ni < 4; ++ni) {
        const int coll = wn * 64 + ni * 16 + l15;
        const int col = n0 + coll;
        if (col < chS) {
            const float sc = 0.25f / denom[coll];
            #pragma unroll
            for (int mi = 0; mi < 4; ++mi)
                #pragma unroll
                for (int rr = 0; rr < 4; ++rr) {
                    const int row = m0 + wm * 64 + mi * 16 + q * 4 + rr;
                    if (row < 196)
                        Cz[(long long)row * ldc + col] = (half_t)(acc[mi][ni][rr] * sc);
                }
        }
    }
}

// ---------------- launcher ----------------
extern "C" void kernel_launch(void* const* d_in, const int* in_sizes, int n_in,
                              void* d_out, int out_size, void* d_ws, size_t ws_size,
                              hipStream_t stream)
{
    const float* emb[4]  = {(const float*)d_in[0], (const float*)d_in[1],
                            (const float*)d_in[2], (const float*)d_in[3]};
    const float* emb_all = (const float*)d_in[4];
    const float* Wq[4]   = {(const float*)d_in[5], (const float*)d_in[7],
                            (const float*)d_in[9], (const float*)d_in[11]};
    const float* Wo[4]   = {(const float*)d_in[6], (const float*)d_in[8],
                            (const float*)d_in[10], (const float*)d_in[12]};
    const float* Wk = (const float*)d_in[13];
    const float* Wv = (const float*)d_in[14];
    float* out = (float*)d_out;

    half_t* hb = (half_t*)d_ws;
    half_t* EAh = hb;                              // 3010560
    half_t* Eh  = EAh + 3010560;                   // 3010560
    half_t* Wkh = Eh  + 3010560;                   // 3686400
    half_t* Wvh = Wkh + 3686400;                   // 3686400
    half_t* Wqh = Wvh + 3686400;                   // 1392640
    half_t* Wo4 = Wqh + 1392640;                   // 1392640
    half_t* KT  = Wo4 + 1392640;                   // [h][b][960][208]      = 12779520
    half_t* Vh  = KT  + 12779520;                  // [h][3136][960]        = 12042240
    half_t* QtT = Vh  + 12042240;                  // per-scale [64][ch][208] = 12779520
    half_t* Ctx = QtT + 12779520;                  // per-scale [16][196][4ch] = 12042240
    half_t* Sch = Ctx + 12042240;                  // per-scale [64][ch][960] raw = 58982400
    float*  Part = (float*)(Sch + 58982400);       // 4 * 64 * 240 floats

    const int  chs[4]   = {64, 128, 256, 512};
    const int  lg2c[4]  = {6, 7, 8, 9};
    const long long offE[4]   = {0, 200704, 602112, 1404928};
    const long long offQ[4]   = {0, 16384, 81920, 344064};
    const long long offQt[4]  = {0, 851968, 2555904, 5963776};
    const long long offSc[4]  = {0, 3932160, 11796480, 27525120};
    const long long offCtx[4] = {0, 802816, 2408448, 5619712};
    const long long ooff[4]   = {0, 200704, 602112, 1404928};
    const float inv_sqrt_kv = 0.03227486121839514f;

    // ---- prep ----
    PrepArgs pa;
    pa.src[0] = emb_all; pa.dst[0] = EAh; pa.n[0] = 3010560; pa.mode[0] = 0; pa.lg2[0] = 0;
    for (int i = 0; i < 4; ++i) {
        pa.src[1 + i] = emb[i]; pa.dst[1 + i] = Eh + offE[i];
        pa.n[1 + i] = (int)(3136LL * chs[i]); pa.mode[1 + i] = 0; pa.lg2[1 + i] = 0;
    }
    pa.src[5] = Wk; pa.dst[5] = Wkh; pa.n[5] = 3686400; pa.mode[5] = 0; pa.lg2[5] = 0;
    pa.src[6] = Wv; pa.dst[6] = Wvh; pa.n[6] = 3686400; pa.mode[6] = 0; pa.lg2[6] = 0;
    for (int i = 0; i < 4; ++i) {
        pa.src[7 + i] = Wq[i]; pa.dst[7 + i] = Wqh + offQ[i];
        pa.n[7 + i] = 4 * chs[i] * chs[i]; pa.mode[7 + i] = 0; pa.lg2[7 + i] = 0;
        pa.src[11 + i] = Wo[i]; pa.dst[11 + i] = Wo4 + offQ[i];
        pa.n[11 + i] = chs[i] * chs[i]; pa.mode[11 + i] = 1; pa.lg2[11 + i] = lg2c[i];
    }
    prep_k<<<dim3(1800, 15), 256, 0, stream>>>(pa);

    // ---- K-proj + V-proj + Q-proj (all scales) in ONE 128x128 launch ----
    {
        BP p{};
        // slot 0: K projection -> KT[h][b][j][n208] (transposed, row-split over 196)
        p.A[0] = EAh; p.B[0] = Wkh; p.C[0] = KT;
        p.Mlim[0] = 3136; p.Nlim[0] = 960; p.Klim[0] = 960; p.nKt[0] = 30;
        p.lda[0] = 960; p.ldb[0] = 960; p.ldc[0] = 208;
        p.divA[0] = 1; p.sAhi[0] = 0; p.sAlo[0] = 0;
        p.divB[0] = 1; p.sBhi[0] = 921600; p.sBlo[0] = 0;
        p.divC[0] = 1; p.sChi[0] = 3194880; p.sClo[0] = 0;
        p.tStrB[0] = 199680; p.tComp[0] = 1; p.outMode[0] = 2; p.alpha[0] = 1.0f;
        p.mT[0] = 25; p.nT[0] = 8;
        // slot 1: V projection -> Vh[h][3136][960] (normal)
        p.A[1] = EAh; p.B[1] = Wvh; p.C[1] = Vh;
        p.Mlim[1] = 3136; p.Nlim[1] = 960; p.Klim[1] = 960; p.nKt[1] = 30;
        p.lda[1] = 960; p.ldb[1] = 960; p.ldc[1] = 960;
        p.divA[1] = 1; p.sAhi[1] = 0; p.sAlo[1] = 0;
        p.divB[1] = 1; p.sBhi[1] = 921600; p.sBlo[1] = 0;
        p.divC[1] = 1; p.sChi[1] = 3010560; p.sClo[1] = 0;
        p.tStrB[1] = 0; p.tComp[1] = 0; p.outMode[1] = 1; p.alpha[1] = 1.0f;
        p.mT[1] = 25; p.nT[1] = 8;
        // slots 2..5: Q-proj per scale -> QtT[z][d][n208] (transposed, no row-split)
        for (int i = 0; i < 4; ++i) {
            const int sl = 2 + i, ch = chs[i];
            p.A[sl] = Eh + offE[i]; p.B[sl] = Wqh + offQ[i]; p.C[sl] = QtT + offQt[i];
            p.Mlim[sl] = 196; p.Nlim[sl] = ch; p.Klim[sl] = ch; p.nKt[sl] = ch / 32;
            p.lda[sl] = ch; p.ldb[sl] = ch; p.ldc[sl] = 208;
            p.divA[sl] = 4; p.sAhi[sl] = 196LL * ch; p.sAlo[sl] = 0;
            p.divB[sl] = 4; p.sBhi[sl] = 0; p.sBlo[sl] = (long long)ch * ch;
            p.divC[sl] = 1; p.sChi[sl] = 208LL * ch; p.sClo[sl] = 0;
            p.tStrB[sl] = 0; p.tComp[sl] = 0; p.outMode[sl] = 2; p.alpha[sl] = 1.0f;
            p.mT[sl] = 2; p.nT[sl] = (ch + 127) / 128;
        }
        int cum = 0;
        const int blocks[6] = {800, 800, 128, 128, 256, 512};
        for (int sl = 0; sl < 6; ++sl) { cum += blocks[sl]; if (sl < 5) p.cumEnd[sl] = cum; }
        p.totW = cum;                       // 2624, divisible by 8
        gemm_w<<<2624, 256, 0, stream>>>(p);
    }

    // ---- Scores (raw) + stats, strip-resident ----
    {
        ScP p{};
        for (int s = 0; s < 4; ++s) {
            p.Qt[s] = QtT + offQt[s];
            p.C[s] = Sch + offSc[s];
            p.Part[s] = Part + (long long)s * 64 * 240;
            p.Mlim[s] = chs[s];
            p.sA[s] = 208LL * chs[s];
            p.sC[s] = 960LL * chs[s];
        }
        p.KT = KT;
        p.alpha = inv_sqrt_kv;
        gemm_s<<<512, 256, 0, stream>>>(p);
    }

    // ---- ctx: fused exp/softmax + PV (pipelined) ----
    {
        CtxP p{};
        p.V = Vh;
        const int nP[4] = {1, 1, 2, 4};
        for (int s = 0; s < 4; ++s) {
            p.S[s] = Sch + offSc[s];
            p.C[s] = Ctx + offCtx[s];
            p.Part[s] = Part + (long long)s * 64 * 240;
            p.ch[s] = chs[s];
            p.nPart[s] = nP[s];
            p.pinv[s] = 1.0f / (chs[s] * 960);
        }
        ctx_k<<<1024, 256, 0, stream>>>(p);
    }

    // ---- out-proj, all scales: out fp32 = Ctx (196 x 4ch) x Wo4^T (64x64) ----
    {
        BP p{};
        int cum = 0;
        for (int s = 0; s < 4; ++s) {
            const int ch = chs[s];
            p.A[s] = Ctx + offCtx[s]; p.B[s] = Wo4 + offQ[s]; p.C[s] = out + ooff[s];
            p.Mlim[s] = 196; p.Nlim[s] = ch; p.Klim[s] = 4 * ch; p.nKt[s] = ch / 8;
            p.lda[s] = 4 * ch; p.ldb[s] = 4 * ch; p.ldc[s] = ch;
            p.divA[s] = 1; p.sAhi[s] = 784LL * ch; p.sAlo[s] = 0;
            p.divB[s] = 1; p.sBhi[s] = 0; p.sBlo[s] = 0;
            p.divC[s] = 1; p.sChi[s] = 196LL * ch; p.sClo[s] = 0;
            p.tStrB[s] = 0; p.tComp[s] = 0; p.outMode[s] = 0; p.alpha[s] = 1.0f;
            p.mT[s] = 4; p.nT[s] = ch / 64;
            cum += 4 * (ch / 64) * 16;
            if (s < 3) p.cumEnd[s] = cum;
        }
        p.cumEnd[3] = p.cumEnd[4] = cum;
        p.totW = cum;
        gemm_b<<<960, 128, 0, stream>>>(p);
    }
}